// Round 13
// baseline (358.272 us; speedup 1.0000x reference)
//
#include <hip/hip_runtime.h>
#include <math.h>

#define H 18
#define NS 65536
#define AD 4
#define HAD 72
#define ITERS 6
#define DELTA 16.0f
#define SCAP 2048
#define PFCAP 4096

__device__ __forceinline__ unsigned encf(float f) {
    unsigned u = __float_as_uint(f);
    return (u & 0x80000000u) ? ~u : (u | 0x80000000u);
}
__device__ __forceinline__ float decf(unsigned u) {
    return __uint_as_float((u & 0x80000000u) ? (u & 0x7FFFFFFFu) : ~u);
}
__device__ __forceinline__ float clamp4f(float x) { return fminf(fmaxf(x, -4.0f), 4.0f); }
// descending u64 order == value desc, then index asc (matches top_k tie-break)
__device__ __forceinline__ unsigned long long packkey(float v, unsigned idx) {
    return ((unsigned long long)encf(v) << 32) | (unsigned long long)(~idx);
}

// Iter 0: evaluate pi and cem0 (2-lane split per candidate, 9+9 hoisted loads),
// write dense v arrays + per-wave(32) maxima + meanarr[0]. No reduce needed
// (mean0 = pi[:,0,:] is known directly).
__global__ void __launch_bounds__(256) k_value0(
        const float4* __restrict__ pi4, const float4* __restrict__ nz4,
        const float* __restrict__ target, float* __restrict__ meanarr,
        float* __restrict__ v_pi, float* __restrict__ wmax_pi,
        float* __restrict__ v_c0, float* __restrict__ wmax_c0) {
    __shared__ float tgt[HAD], mnL[HAD];
    const int tid = threadIdx.x, wg = blockIdx.x;
    const int lane = tid & 63, wid = tid >> 6;
    const int half = lane >> 5;
    const int n = wg * 128 + wid * 32 + (lane & 31);

    float4 xs[9], ps[9];
#pragma unroll
    for (int hh = 0; hh < 9; ++hh) xs[hh] = nz4[(size_t)(half * 9 + hh) * NS + n];
#pragma unroll
    for (int hh = 0; hh < 9; ++hh) ps[hh] = pi4[(size_t)(half * 9 + hh) * NS + n];

    if (tid < HAD) {
        tgt[tid] = target[tid];
        float m0 = ((const float*)pi4)[(size_t)(tid >> 2) * NS * AD + (tid & 3)];
        mnL[tid] = m0;
        meanarr[tid] = m0;   // identical from all blocks: benign
    }
    __syncthreads();

    float a2 = 0.f, p2 = 0.f;
#pragma unroll
    for (int hh = 0; hh < 9; ++hh) {
        const int h = half * 9 + hh;
        float c;
        c = clamp4f(mnL[h*4+0] + 0.5f * xs[hh].x) - tgt[h*4+0]; a2 += c*c;
        c = clamp4f(mnL[h*4+1] + 0.5f * xs[hh].y) - tgt[h*4+1]; a2 += c*c;
        c = clamp4f(mnL[h*4+2] + 0.5f * xs[hh].z) - tgt[h*4+2]; a2 += c*c;
        c = clamp4f(mnL[h*4+3] + 0.5f * xs[hh].w) - tgt[h*4+3]; a2 += c*c;
        c = ps[hh].x - tgt[h*4+0]; p2 += c*c;
        c = ps[hh].y - tgt[h*4+1]; p2 += c*c;
        c = ps[hh].z - tgt[h*4+2]; p2 += c*c;
        c = ps[hh].w - tgt[h*4+3]; p2 += c*c;
    }
    const float vc = -(a2 + __shfl_xor(a2, 32));
    const float vp = -(p2 + __shfl_xor(p2, 32));
    if (half == 0) { v_c0[n] = vc; v_pi[n] = vp; }
    float mc = vc, mp = vp;
    for (int off = 16; off; off >>= 1) {
        mc = fmaxf(mc, __shfl_xor(mc, off));
        mp = fmaxf(mp, __shfl_xor(mp, off));
    }
    if (lane == 0) { wmax_c0[wg * 4 + wid] = mc; wmax_pi[wg * 4 + wid] = mp; }
}

// Iters 1..5 fused: block 0 reduces iter-1 (hierarchical scan of wave maxima
// -> survivor chunks only -> bitonic top-64 -> softmax -> gather -> mean_i),
// then release-fence + flag. Other 255 blocks prefetch their noise into regs
// and spin on the flag (relaxed poll, one acquire fence). Then all evaluate
// cem_i (scale=1) and write dense v + per-wave(64) maxima.
__global__ void __launch_bounds__(256) k_step(
        const float* __restrict__ pi, const float* __restrict__ noise,
        const float* __restrict__ target, float* __restrict__ meanarr,
        float* __restrict__ pimaxp, unsigned* __restrict__ pfcnt,
        unsigned long long* __restrict__ pfk, unsigned* __restrict__ flags,
        const float* __restrict__ v_pi, const float* __restrict__ wmax_pi,
        const float* __restrict__ v_prev, const float* __restrict__ wmax_prev,
        int nprev, int glog,
        float* __restrict__ v_out, float* __restrict__ wmax_out, int iter) {
    __shared__ unsigned long long skey[SCAP];
    __shared__ float buf[64 * 73];
    __shared__ float w64[64];
    __shared__ float tgt[HAD], mnL[HAD], mprev[HAD];
    __shared__ float redf[4];
    __shared__ unsigned s_fcnt, s_pf;
    __shared__ float s_S, s_gmax, s_pimax;

    const int tid = threadIdx.x, wg = blockIdx.x;
    const int lane = tid & 63, wid = tid >> 6;
    const int n = wg * 256 + tid;
    const int is_first = (iter == 1);

    // hoist this iteration's noise loads (independent of the mean handshake)
    const float4* nz4 = (const float4*)(noise + (size_t)iter * H * NS * AD);
    float4 xs[H];
#pragma unroll
    for (int h = 0; h < H; ++h) xs[h] = nz4[(size_t)h * NS + n];

    if (tid < HAD) tgt[tid] = target[tid];

    if (wg == 0) {
        // ---------------- reduce for iter-1 ----------------
        if (tid < HAD) mprev[tid] = meanarr[(iter - 1) * HAD + tid];
        if (tid == 0) { s_fcnt = 0u; s_pf = 0u; }
        __syncthreads();
        if (is_first) {
            float g = -INFINITY;
            for (int k = tid; k < 2048; k += 256) g = fmaxf(g, wmax_pi[k]);
            for (int off = 32; off; off >>= 1) g = fmaxf(g, __shfl_xor(g, off));
            if (lane == 0) redf[wid] = g;
            __syncthreads();
            if (tid == 0) {
                s_pimax = fmaxf(fmaxf(redf[0], redf[1]), fmaxf(redf[2], redf[3]));
                *pimaxp = s_pimax;
            }
        } else {
            if (tid == 0) s_pimax = *pimaxp;
        }
        __syncthreads();
        {
            float g = -INFINITY;
            for (int k = tid; k < nprev; k += 256) g = fmaxf(g, wmax_prev[k]);
            for (int off = 32; off; off >>= 1) g = fmaxf(g, __shfl_xor(g, off));
            if (lane == 0) redf[wid] = g;
            __syncthreads();
            if (tid == 0)
                s_gmax = fmaxf(s_pimax, fmaxf(fmaxf(redf[0], redf[1]), fmaxf(redf[2], redf[3])));
        }
        __syncthreads();
        const float gmax = s_gmax, thr = gmax - DELTA;

        // pi side
        if (is_first) {
            const float pthr = s_pimax - DELTA;    // pthr <= thr
            for (int c = tid; c < 2048; c += 256) {
                if (wmax_pi[c] >= pthr) {
                    const float4* vp4 = (const float4*)v_pi + c * 8;
                    for (int q = 0; q < 8; ++q) {
                        float4 x = vp4[q];
                        float vv[4] = {x.x, x.y, x.z, x.w};
#pragma unroll
                        for (int c2 = 0; c2 < 4; ++c2) {
                            float val = vv[c2];
                            if (val >= pthr) {
                                unsigned long long key = packkey(val, (unsigned)(c * 32 + q * 4 + c2));
                                unsigned p = atomicAdd(&s_pf, 1u);
                                if (p < PFCAP) pfk[p] = key;
                                if (val >= thr) {
                                    unsigned p2i = atomicAdd(&s_fcnt, 1u);
                                    if (p2i < SCAP) skey[p2i] = key;
                                }
                            }
                        }
                    }
                }
            }
        } else {
            unsigned pc = *pfcnt; if (pc > PFCAP) pc = PFCAP;
            for (unsigned k = tid; k < pc; k += 256) {
                unsigned long long key = pfk[k];
                if (decf((unsigned)(key >> 32)) >= thr) {
                    unsigned p = atomicAdd(&s_fcnt, 1u);
                    if (p < SCAP) skey[p] = key;
                }
            }
        }
        // cem side (chunks of 1<<glog candidates)
        {
            const int cs = 1 << glog;
            for (int c = tid; c < nprev; c += 256) {
                if (wmax_prev[c] >= thr) {
                    const float4* vc4 = (const float4*)v_prev + c * (cs / 4);
                    for (int q = 0; q < cs / 4; ++q) {
                        float4 x = vc4[q];
                        float vv[4] = {x.x, x.y, x.z, x.w};
#pragma unroll
                        for (int c2 = 0; c2 < 4; ++c2) {
                            float val = vv[c2];
                            if (val >= thr) {
                                unsigned p = atomicAdd(&s_fcnt, 1u);
                                if (p < SCAP) skey[p] = packkey(val, (unsigned)(NS + c * cs + q * 4 + c2));
                            }
                        }
                    }
                }
            }
        }
        __syncthreads();
        if (is_first && tid == 0) *pfcnt = (s_pf > PFCAP) ? PFCAP : s_pf;
        unsigned fc = s_fcnt; if (fc > SCAP) fc = SCAP;
        unsigned P2 = 128; while (P2 < fc) P2 <<= 1;
        for (unsigned k = fc + tid; k < P2; k += 256) skey[k] = 0ull;
        __syncthreads();
        for (unsigned kk = 2; kk <= P2; kk <<= 1) {
            for (unsigned j = kk >> 1; j; j >>= 1) {
                for (unsigned x = tid; x < P2; x += 256) {
                    unsigned l = x ^ j;
                    if (l > x) {
                        unsigned long long k0 = skey[x], k1 = skey[l];
                        bool desc = ((x & kk) == 0);
                        if (desc ? (k0 < k1) : (k0 > k1)) { skey[x] = k1; skey[l] = k0; }
                    }
                }
                __syncthreads();
            }
        }
        const int E = (fc < 64u) ? (int)fc : 64;
        if (tid < 64) {
            float we = (tid < E) ? expf(decf((unsigned)(skey[tid] >> 32)) - gmax) : 0.0f;
            w64[tid] = we;
            float s = we;
            for (int off = 32; off; off >>= 1) s += __shfl_xor(s, off);
            if (tid == 0) s_S = s;
        }
        __syncthreads();
        const float invS = 1.0f / (s_S * (1.0f + 1e-9f));
        const float pscale = is_first ? 0.5f : 1.0f;
        const float* nzp = noise + (size_t)(iter - 1) * H * NS * AD;
        for (int el = tid; el < 64 * HAD; el += 256) {
            const int e = el / HAD, j = el - e * HAD;
            const int h = j >> 2, aa = j & 3;
            float av = 0.f;
            if (e < E) {
                const unsigned idx = (unsigned)~(unsigned)(skey[e] & 0xFFFFFFFFull);
                if (idx < NS) av = pi[(size_t)h * NS * AD + (size_t)idx * AD + aa];
                else av = clamp4f(mprev[j] + pscale * nzp[(size_t)h * NS * AD + (size_t)(idx - NS) * AD + aa]);
                av *= w64[e];
            }
            buf[e * 73 + j] = av;
        }
        __syncthreads();
        if (tid < HAD) {
            float s = 0.f;
#pragma unroll 8
            for (int e = 0; e < 64; ++e) s += buf[e * 73 + tid];
            meanarr[iter * HAD + tid] = 0.1f * mprev[tid] + 0.9f * (s * invS);
        }
        __syncthreads();
        if (tid == 0) {
            __builtin_amdgcn_fence(__ATOMIC_RELEASE, "agent");
            __hip_atomic_store(&flags[iter], 1u, __ATOMIC_RELAXED, __HIP_MEMORY_SCOPE_AGENT);
        }
    } else {
        // force the prefetched loads to complete while block 0 reduces
#pragma unroll
        for (int h = 0; h < H; ++h)
            asm volatile("" :: "v"(xs[h].x), "v"(xs[h].y), "v"(xs[h].z), "v"(xs[h].w));
        if (tid == 0) {
            while (__hip_atomic_load(&flags[iter], __ATOMIC_RELAXED, __HIP_MEMORY_SCOPE_AGENT) == 0u)
                __builtin_amdgcn_s_sleep(2);
        }
        __syncthreads();
        __builtin_amdgcn_fence(__ATOMIC_ACQUIRE, "agent");
    }

    // -------- phase A: evaluate cem_iter (scale = 1.0 for iters >= 1) --------
    if (tid < HAD) mnL[tid] = meanarr[iter * HAD + tid];
    __syncthreads();
    float a2 = 0.f;
#pragma unroll
    for (int h = 0; h < H; ++h) {
        float c;
        c = clamp4f(mnL[h*4+0] + xs[h].x) - tgt[h*4+0]; a2 += c*c;
        c = clamp4f(mnL[h*4+1] + xs[h].y) - tgt[h*4+1]; a2 += c*c;
        c = clamp4f(mnL[h*4+2] + xs[h].z) - tgt[h*4+2]; a2 += c*c;
        c = clamp4f(mnL[h*4+3] + xs[h].w) - tgt[h*4+3]; a2 += c*c;
    }
    const float vc = -a2;
    v_out[n] = vc;
    float m = vc;
    for (int off = 32; off; off >>= 1) m = fmaxf(m, __shfl_xor(m, off));
    if (lane == 0) wmax_out[wg * 4 + wid] = m;
}

// Final: reduce iter 5 in argmax-only mode; gather winner's actions -> out.
__global__ void __launch_bounds__(1024) k_final(
        const float* __restrict__ pi, const float* __restrict__ noise,
        const float* __restrict__ meanarr, const float* __restrict__ pimaxp,
        const unsigned* __restrict__ pfcnt, const unsigned long long* __restrict__ pfk,
        const float* __restrict__ v5, const float* __restrict__ wmax5,
        float* __restrict__ out) {
    __shared__ float redf[16];
    __shared__ unsigned long long redk[16];
    __shared__ float s_gmax;
    __shared__ float mnL[HAD];
    const int tid = threadIdx.x, lane = tid & 63, wid = tid >> 6;
    if (tid < HAD) mnL[tid] = meanarr[5 * HAD + tid];
    {
        float g = wmax5[tid];   // 1024 entries, 1024 threads
        for (int off = 32; off; off >>= 1) g = fmaxf(g, __shfl_xor(g, off));
        if (lane == 0) redf[wid] = g;
        __syncthreads();
        if (tid == 0) {
            float x = redf[0];
            for (int q = 1; q < 16; ++q) x = fmaxf(x, redf[q]);
            s_gmax = fmaxf(x, *pimaxp);
        }
        __syncthreads();
    }
    const float thr = s_gmax - DELTA;
    unsigned long long bk = 0ull;
    {
        unsigned pc = *pfcnt; if (pc > PFCAP) pc = PFCAP;
        for (unsigned k = tid; k < pc; k += 1024) {
            unsigned long long key = pfk[k];
            if (key > bk) bk = key;
        }
    }
    {
        const int c = tid;   // one 64-candidate chunk per thread
        if (wmax5[c] >= thr) {
            const float4* v4 = (const float4*)v5 + c * 16;
            for (int q = 0; q < 16; ++q) {
                float4 x = v4[q];
                float vv[4] = {x.x, x.y, x.z, x.w};
#pragma unroll
                for (int c2 = 0; c2 < 4; ++c2) {
                    float val = vv[c2];
                    if (val >= thr) {
                        unsigned long long key = packkey(val, (unsigned)(NS + c * 64 + q * 4 + c2));
                        if (key > bk) bk = key;
                    }
                }
            }
        }
    }
    for (int off = 32; off; off >>= 1) {
        unsigned long long ok = __shfl_xor(bk, off);
        if (ok > bk) bk = ok;
    }
    if (lane == 0) redk[wid] = bk;
    __syncthreads();
    if (tid == 0) {
        unsigned long long b = redk[0];
        for (int q = 1; q < 16; ++q) if (redk[q] > b) b = redk[q];
        redk[0] = b;
    }
    __syncthreads();
    const unsigned idx = (unsigned)~(unsigned)(redk[0] & 0xFFFFFFFFull);
    if (tid < HAD) {
        const int h = tid >> 2, aa = tid & 3;
        float o;
        if (idx < NS) o = pi[(size_t)h * NS * AD + (size_t)idx * AD + aa];
        else o = clamp4f(mnL[tid] + noise[(size_t)5 * H * NS * AD + (size_t)h * NS * AD + (size_t)(idx - NS) * AD + aa]);
        out[tid] = o;
    }
}

extern "C" void kernel_launch(void* const* d_in, const int* in_sizes, int n_in,
                              void* d_out, int out_size, void* d_ws, size_t ws_size,
                              hipStream_t stream) {
    const float* pi     = (const float*)d_in[0];
    const float* noise  = (const float*)d_in[1];
    const float* target = (const float*)d_in[2];
    float* out = (float*)d_out;

    float* ws = (float*)d_ws;
    float* meanarr  = ws;                                  // 8*72 (pad 1024)
    float* pimaxp   = ws + 1024;                           // 1
    unsigned* pfcnt = (unsigned*)(pimaxp + 1);             // 1
    unsigned* flags = pfcnt + 1;                           // 8 (memset per call)
    float* wmax_pi  = (float*)(flags + 8);                 // 2048
    float* wmax_c0  = wmax_pi + 2048;                      // 2048
    float* wmax_c   = wmax_c0 + 2048;                      // 5*1024
    float* v_pi     = wmax_c + 5 * 1024;                   // NS
    float* v_c      = v_pi + NS;                           // 6*NS
    unsigned long long* pfk =
        (unsigned long long*)(((size_t)(v_c + 6 * NS) + 15) & ~(size_t)15);  // PFCAP

    (void)hipMemsetAsync(flags, 0, 8 * sizeof(unsigned), stream);
    k_value0<<<512, 256, 0, stream>>>((const float4*)pi, (const float4*)noise,
                                      target, meanarr, v_pi, wmax_pi, v_c, wmax_c0);
    for (int i = 1; i < ITERS; ++i) {
        const float* v_prev = v_c + (size_t)(i - 1) * NS;
        const float* wmp; int np, gl;
        if (i == 1) { wmp = wmax_c0; np = 2048; gl = 5; }
        else        { wmp = wmax_c + (size_t)(i - 2) * 1024; np = 1024; gl = 6; }
        k_step<<<256, 256, 0, stream>>>(pi, noise, target, meanarr, pimaxp, pfcnt,
                                        pfk, flags, v_pi, wmax_pi, v_prev, wmp, np, gl,
                                        v_c + (size_t)i * NS,
                                        wmax_c + (size_t)(i - 1) * 1024, i);
    }
    k_final<<<1, 1024, 0, stream>>>(pi, noise, meanarr, pimaxp, pfcnt, pfk,
                                    v_c + (size_t)5 * NS, wmax_c + (size_t)4 * 1024, out);
}

// Round 14
// 302.300 us; speedup vs baseline: 1.1852x; 1.1852x over previous
//
#include <hip/hip_runtime.h>
#include <math.h>

#define H 18
#define NS 65536
#define AD 4
#define HAD 72
#define ITERS 6
#define DELTA 16.0f
#define SCAP 2048
#define NCH 2048          // 32-candidate chunks per candidate set

__device__ __forceinline__ unsigned encf(float f) {
    unsigned u = __float_as_uint(f);
    return (u & 0x80000000u) ? ~u : (u | 0x80000000u);
}
__device__ __forceinline__ float decf(unsigned u) {
    return __uint_as_float((u & 0x80000000u) ? (u & 0x7FFFFFFFu) : ~u);
}
__device__ __forceinline__ float clamp4f(float x) { return fminf(fmaxf(x, -4.0f), 4.0f); }
// descending u64 order == value desc, then index asc (matches top_k tie-break)
__device__ __forceinline__ unsigned long long packkey(float v, unsigned idx) {
    return ((unsigned long long)encf(v) << 32) | (unsigned long long)(~idx);
}

// ---- iter 0: evaluate pi and cem0 (2 lanes per candidate, 9+9 hoisted
//      loads), write dense v + 32-candidate chunk maxima + meanarr[0].
__global__ void __launch_bounds__(256) k_value0(
        const float4* __restrict__ pi4, const float4* __restrict__ nz4,
        const float* __restrict__ target, float* __restrict__ meanarr,
        float* __restrict__ v_pi, float* __restrict__ wmax_pi,
        float* __restrict__ v_c0, float* __restrict__ wmax_c0) {
    __shared__ float tgt[HAD], mnL[HAD];
    const int tid = threadIdx.x, wg = blockIdx.x;
    const int lane = tid & 63, wid = tid >> 6;
    const int half = lane >> 5;
    const int n = wg * 128 + wid * 32 + (lane & 31);

    float4 xs[9], ps[9];
#pragma unroll
    for (int hh = 0; hh < 9; ++hh) xs[hh] = nz4[(size_t)(half * 9 + hh) * NS + n];
#pragma unroll
    for (int hh = 0; hh < 9; ++hh) ps[hh] = pi4[(size_t)(half * 9 + hh) * NS + n];

    if (tid < HAD) {
        tgt[tid] = target[tid];
        float m0 = ((const float*)pi4)[(size_t)(tid >> 2) * NS * AD + (tid & 3)];
        mnL[tid] = m0;
        meanarr[tid] = m0;   // identical from all blocks: benign
    }
    __syncthreads();

    float a2 = 0.f, p2 = 0.f;
#pragma unroll
    for (int hh = 0; hh < 9; ++hh) {
        const int h = half * 9 + hh;
        float c;
        c = clamp4f(mnL[h*4+0] + 0.5f * xs[hh].x) - tgt[h*4+0]; a2 += c*c;
        c = clamp4f(mnL[h*4+1] + 0.5f * xs[hh].y) - tgt[h*4+1]; a2 += c*c;
        c = clamp4f(mnL[h*4+2] + 0.5f * xs[hh].z) - tgt[h*4+2]; a2 += c*c;
        c = clamp4f(mnL[h*4+3] + 0.5f * xs[hh].w) - tgt[h*4+3]; a2 += c*c;
        c = ps[hh].x - tgt[h*4+0]; p2 += c*c;
        c = ps[hh].y - tgt[h*4+1]; p2 += c*c;
        c = ps[hh].z - tgt[h*4+2]; p2 += c*c;
        c = ps[hh].w - tgt[h*4+3]; p2 += c*c;
    }
    const float vc = -(a2 + __shfl_xor(a2, 32));
    const float vp = -(p2 + __shfl_xor(p2, 32));
    if (half == 0) { v_c0[n] = vc; v_pi[n] = vp; }
    float mc = vc, mp = vp;
    for (int off = 32; off; off >>= 1) {
        mc = fmaxf(mc, __shfl_xor(mc, off));
        mp = fmaxf(mp, __shfl_xor(mp, off));
    }
    if (lane == 0) { wmax_c0[wg * 4 + wid] = mc; wmax_pi[wg * 4 + wid] = mp; }
}

// ---- iters 1..5: EVERY block redundantly reduces iter-1 (hierarchical
//      chunk-max scan -> survivors -> bitonic top-64 -> softmax -> gather ->
//      mean_i in LDS + meanarr[i]), then evaluates its slice of cem_i.
__global__ void __launch_bounds__(256) k_fused(
        const float* __restrict__ pi, const float* __restrict__ noise,
        const float* __restrict__ target, float* __restrict__ meanarr,
        const float* __restrict__ wmax_pi, const float* __restrict__ v_pi,
        const float* __restrict__ wmax_prev, const float* __restrict__ v_prev,
        float* __restrict__ v_out, float* __restrict__ wmax_out, int iter) {
    __shared__ unsigned long long skey[SCAP];
    __shared__ float buf[64 * 73];
    __shared__ float w64[64];
    __shared__ float tgt[HAD], mnL[HAD], mprev[HAD];
    __shared__ float redf[4];
    __shared__ unsigned s_fcnt;
    __shared__ float s_S, s_gmax;

    const int tid = threadIdx.x, wg = blockIdx.x;
    const int lane = tid & 63, wid = tid >> 6;

    if (tid < HAD) {
        tgt[tid] = target[tid];
        mprev[tid] = meanarr[(iter - 1) * HAD + tid];
    }
    if (tid == 0) s_fcnt = 0u;
    __syncthreads();

    // ---- gmax over pi ∪ cem_{iter-1}
    {
        float g = -INFINITY;
        for (int k = tid; k < NCH; k += 256)
            g = fmaxf(g, fmaxf(wmax_pi[k], wmax_prev[k]));
        for (int off = 32; off; off >>= 1) g = fmaxf(g, __shfl_xor(g, off));
        if (lane == 0) redf[wid] = g;
        __syncthreads();
        if (tid == 0)
            s_gmax = fmaxf(fmaxf(redf[0], redf[1]), fmaxf(redf[2], redf[3]));
        __syncthreads();
    }
    const float gmax = s_gmax, thr = gmax - DELTA;

    // ---- survivor collection: only chunks whose max passes the threshold
    for (int c = tid; c < NCH; c += 256) {
        if (wmax_pi[c] >= thr) {
            const float4* v4 = (const float4*)v_pi + c * 8;
            for (int q = 0; q < 8; ++q) {
                float4 x = v4[q];
                float vv[4] = {x.x, x.y, x.z, x.w};
#pragma unroll
                for (int c2 = 0; c2 < 4; ++c2) {
                    if (vv[c2] >= thr) {
                        unsigned p = atomicAdd(&s_fcnt, 1u);
                        if (p < SCAP) skey[p] = packkey(vv[c2], (unsigned)(c * 32 + q * 4 + c2));
                    }
                }
            }
        }
        if (wmax_prev[c] >= thr) {
            const float4* v4 = (const float4*)v_prev + c * 8;
            for (int q = 0; q < 8; ++q) {
                float4 x = v4[q];
                float vv[4] = {x.x, x.y, x.z, x.w};
#pragma unroll
                for (int c2 = 0; c2 < 4; ++c2) {
                    if (vv[c2] >= thr) {
                        unsigned p = atomicAdd(&s_fcnt, 1u);
                        if (p < SCAP) skey[p] = packkey(vv[c2], (unsigned)(NS + c * 32 + q * 4 + c2));
                    }
                }
            }
        }
    }
    __syncthreads();
    unsigned fc = s_fcnt; if (fc > SCAP) fc = SCAP;

    // ---- bitonic sort desc on packed keys (deterministic total order)
    unsigned P2 = 128; while (P2 < fc) P2 <<= 1;
    for (unsigned k = fc + tid; k < P2; k += 256) skey[k] = 0ull;
    __syncthreads();
    for (unsigned kk = 2; kk <= P2; kk <<= 1) {
        for (unsigned j = kk >> 1; j; j >>= 1) {
            for (unsigned x = tid; x < P2; x += 256) {
                unsigned l = x ^ j;
                if (l > x) {
                    unsigned long long k0 = skey[x], k1 = skey[l];
                    bool desc = ((x & kk) == 0);
                    if (desc ? (k0 < k1) : (k0 > k1)) { skey[x] = k1; skey[l] = k0; }
                }
            }
            __syncthreads();
        }
    }
    const int E = (fc < 64u) ? (int)fc : 64;
    if (tid < 64) {
        float we = (tid < E) ? expf(decf((unsigned)(skey[tid] >> 32)) - gmax) : 0.0f;
        w64[tid] = we;
        float s = we;
        for (int off = 32; off; off >>= 1) s += __shfl_xor(s, off);
        if (tid == 0) s_S = s;
    }
    __syncthreads();
    const float invS = 1.0f / (s_S * (1.0f + 1e-9f));
    const float pscale = (iter == 1) ? 0.5f : 1.0f;
    const float* nzp = noise + (size_t)(iter - 1) * H * NS * AD;
    for (int el = tid; el < 64 * HAD; el += 256) {
        const int e = el / HAD, j = el - e * HAD;
        const int h = j >> 2, aa = j & 3;
        float av = 0.f;
        if (e < E) {
            const unsigned idx = (unsigned)~(unsigned)(skey[e] & 0xFFFFFFFFull);
            if (idx < NS) av = pi[(size_t)h * NS * AD + (size_t)idx * AD + aa];
            else av = clamp4f(mprev[j] + pscale * nzp[(size_t)h * NS * AD + (size_t)(idx - NS) * AD + aa]);
            av *= w64[e];
        }
        buf[e * 73 + j] = av;
    }
    __syncthreads();
    if (tid < HAD) {
        float s = 0.f;
#pragma unroll 8
        for (int e = 0; e < 64; ++e) s += buf[e * 73 + tid];
        float nm = 0.1f * mprev[tid] + 0.9f * (s * invS);
        mnL[tid] = nm;
        meanarr[iter * HAD + tid] = nm;   // identical from all blocks: benign
    }
    __syncthreads();

    // ---- phase A: evaluate cem_iter (scale = 1.0 for iters >= 1)
    const int half = lane >> 5;
    const int n = wg * 128 + wid * 32 + (lane & 31);
    const float4* nz4 = (const float4*)(noise + (size_t)iter * H * NS * AD);
    float4 xs[9];
#pragma unroll
    for (int hh = 0; hh < 9; ++hh) xs[hh] = nz4[(size_t)(half * 9 + hh) * NS + n];
    float a2 = 0.f;
#pragma unroll
    for (int hh = 0; hh < 9; ++hh) {
        const int h = half * 9 + hh;
        float c;
        c = clamp4f(mnL[h*4+0] + xs[hh].x) - tgt[h*4+0]; a2 += c*c;
        c = clamp4f(mnL[h*4+1] + xs[hh].y) - tgt[h*4+1]; a2 += c*c;
        c = clamp4f(mnL[h*4+2] + xs[hh].z) - tgt[h*4+2]; a2 += c*c;
        c = clamp4f(mnL[h*4+3] + xs[hh].w) - tgt[h*4+3]; a2 += c*c;
    }
    const float vc = -(a2 + __shfl_xor(a2, 32));
    if (half == 0) v_out[n] = vc;
    float m = vc;
    for (int off = 32; off; off >>= 1) m = fmaxf(m, __shfl_xor(m, off));
    if (lane == 0) wmax_out[wg * 4 + wid] = m;
}

// ---- final: exact argmax over pi ∪ cem5 (thr = gmax), gather, write out
__global__ void __launch_bounds__(1024) k_final(
        const float* __restrict__ pi, const float* __restrict__ noise,
        const float* __restrict__ meanarr,
        const float* __restrict__ wmax_pi, const float* __restrict__ v_pi,
        const float* __restrict__ wmax_c5, const float* __restrict__ v_c5,
        float* __restrict__ out) {
    __shared__ float redf[16];
    __shared__ unsigned long long redk[16];
    __shared__ float s_gmax;
    __shared__ float mnL[HAD];
    const int tid = threadIdx.x, lane = tid & 63, wid = tid >> 6;
    if (tid < HAD) mnL[tid] = meanarr[5 * HAD + tid];
    {
        float g = -INFINITY;
        for (int k = tid; k < NCH; k += 1024)
            g = fmaxf(g, fmaxf(wmax_pi[k], wmax_c5[k]));
        for (int off = 32; off; off >>= 1) g = fmaxf(g, __shfl_xor(g, off));
        if (lane == 0) redf[wid] = g;
        __syncthreads();
        if (tid == 0) {
            float x = redf[0];
            for (int q = 1; q < 16; ++q) x = fmaxf(x, redf[q]);
            s_gmax = x;
        }
        __syncthreads();
    }
    const float gmax = s_gmax;
    unsigned long long bk = 0ull;
    for (int c = tid; c < NCH; c += 1024) {
        if (wmax_pi[c] >= gmax) {
            const float4* v4 = (const float4*)v_pi + c * 8;
            for (int q = 0; q < 8; ++q) {
                float4 x = v4[q];
                float vv[4] = {x.x, x.y, x.z, x.w};
#pragma unroll
                for (int c2 = 0; c2 < 4; ++c2)
                    if (vv[c2] >= gmax) {
                        unsigned long long key = packkey(vv[c2], (unsigned)(c * 32 + q * 4 + c2));
                        if (key > bk) bk = key;
                    }
            }
        }
        if (wmax_c5[c] >= gmax) {
            const float4* v4 = (const float4*)v_c5 + c * 8;
            for (int q = 0; q < 8; ++q) {
                float4 x = v4[q];
                float vv[4] = {x.x, x.y, x.z, x.w};
#pragma unroll
                for (int c2 = 0; c2 < 4; ++c2)
                    if (vv[c2] >= gmax) {
                        unsigned long long key = packkey(vv[c2], (unsigned)(NS + c * 32 + q * 4 + c2));
                        if (key > bk) bk = key;
                    }
            }
        }
    }
    for (int off = 32; off; off >>= 1) {
        unsigned long long ok = __shfl_xor(bk, off);
        if (ok > bk) bk = ok;
    }
    if (lane == 0) redk[wid] = bk;
    __syncthreads();
    if (tid == 0) {
        unsigned long long b = redk[0];
        for (int q = 1; q < 16; ++q) if (redk[q] > b) b = redk[q];
        redk[0] = b;
    }
    __syncthreads();
    const unsigned idx = (unsigned)~(unsigned)(redk[0] & 0xFFFFFFFFull);
    if (tid < HAD) {
        const int h = tid >> 2, aa = tid & 3;
        float o;
        if (idx < NS) o = pi[(size_t)h * NS * AD + (size_t)idx * AD + aa];
        else o = clamp4f(mnL[tid] + noise[(size_t)5 * H * NS * AD + (size_t)h * NS * AD + (size_t)(idx - NS) * AD + aa]);
        out[tid] = o;
    }
}

extern "C" void kernel_launch(void* const* d_in, const int* in_sizes, int n_in,
                              void* d_out, int out_size, void* d_ws, size_t ws_size,
                              hipStream_t stream) {
    const float* pi     = (const float*)d_in[0];
    const float* noise  = (const float*)d_in[1];
    const float* target = (const float*)d_in[2];
    float* out = (float*)d_out;

    float* ws = (float*)d_ws;
    float* meanarr = ws;                                   // 8*72 (pad 1024)
    float* wmax_pi = ws + 1024;                            // NCH
    float* wmax_c  = wmax_pi + NCH;                        // 6*NCH
    float* v_pi    = wmax_c + 6 * NCH;                     // NS
    float* v_c     = v_pi + NS;                            // 6*NS

    k_value0<<<512, 256, 0, stream>>>((const float4*)pi, (const float4*)noise,
                                      target, meanarr, v_pi, wmax_pi, v_c, wmax_c);
    for (int i = 1; i < ITERS; ++i)
        k_fused<<<512, 256, 0, stream>>>(pi, noise, target, meanarr,
                                         wmax_pi, v_pi,
                                         wmax_c + (size_t)(i - 1) * NCH,
                                         v_c + (size_t)(i - 1) * NS,
                                         v_c + (size_t)i * NS,
                                         wmax_c + (size_t)i * NCH, i);
    k_final<<<1, 1024, 0, stream>>>(pi, noise, meanarr, wmax_pi, v_pi,
                                    wmax_c + (size_t)5 * NCH,
                                    v_c + (size_t)5 * NS, out);
}

// Round 15
// 139.218 us; speedup vs baseline: 2.5735x; 2.1714x over previous
//
#include <hip/hip_runtime.h>
#include <math.h>

#define H 18
#define NS 65536
#define AD 4
#define HAD 72
#define ITERS 6
#define DELTA 16.0f
#define SCAP 2048
#define NCH 2048          // 32-candidate chunks per candidate set

__device__ __forceinline__ unsigned encf(float f) {
    unsigned u = __float_as_uint(f);
    return (u & 0x80000000u) ? ~u : (u | 0x80000000u);
}
__device__ __forceinline__ float decf(unsigned u) {
    return __uint_as_float((u & 0x80000000u) ? (u & 0x7FFFFFFFu) : ~u);
}
__device__ __forceinline__ float clamp4f(float x) { return fminf(fmaxf(x, -4.0f), 4.0f); }
// descending u64 order == value desc, then index asc (matches top_k tie-break)
__device__ __forceinline__ unsigned long long packkey(float v, unsigned idx) {
    return ((unsigned long long)encf(v) << 32) | (unsigned long long)(~idx);
}

// ---- iter 0: evaluate pi and cem0 (2 lanes per candidate, 9+9 hoisted
//      loads), write dense v + 32-candidate chunk maxima + meanarr[0].
__global__ void __launch_bounds__(256, 2) k_value0(
        const float4* __restrict__ pi4, const float4* __restrict__ nz4,
        const float* __restrict__ target, float* __restrict__ meanarr,
        float* __restrict__ v_pi, float* __restrict__ wmax_pi,
        float* __restrict__ v_c0, float* __restrict__ wmax_c0) {
    __shared__ float tgt[HAD], mnL[HAD];
    const int tid = threadIdx.x, wg = blockIdx.x;
    const int lane = tid & 63, wid = tid >> 6;
    const int half = lane >> 5;
    const int n = wg * 128 + wid * 32 + (lane & 31);

    float4 xs[9], ps[9];
#pragma unroll
    for (int hh = 0; hh < 9; ++hh) xs[hh] = nz4[(size_t)(half * 9 + hh) * NS + n];
#pragma unroll
    for (int hh = 0; hh < 9; ++hh) ps[hh] = pi4[(size_t)(half * 9 + hh) * NS + n];

    if (tid < HAD) {
        tgt[tid] = target[tid];
        float m0 = ((const float*)pi4)[(size_t)(tid >> 2) * NS * AD + (tid & 3)];
        mnL[tid] = m0;
        meanarr[tid] = m0;   // identical from all blocks: benign
    }
    __syncthreads();

    float a2 = 0.f, p2 = 0.f;
#pragma unroll
    for (int hh = 0; hh < 9; ++hh) {
        const int h = half * 9 + hh;
        float c;
        c = clamp4f(mnL[h*4+0] + 0.5f * xs[hh].x) - tgt[h*4+0]; a2 += c*c;
        c = clamp4f(mnL[h*4+1] + 0.5f * xs[hh].y) - tgt[h*4+1]; a2 += c*c;
        c = clamp4f(mnL[h*4+2] + 0.5f * xs[hh].z) - tgt[h*4+2]; a2 += c*c;
        c = clamp4f(mnL[h*4+3] + 0.5f * xs[hh].w) - tgt[h*4+3]; a2 += c*c;
        c = ps[hh].x - tgt[h*4+0]; p2 += c*c;
        c = ps[hh].y - tgt[h*4+1]; p2 += c*c;
        c = ps[hh].z - tgt[h*4+2]; p2 += c*c;
        c = ps[hh].w - tgt[h*4+3]; p2 += c*c;
    }
    const float vc = -(a2 + __shfl_xor(a2, 32));
    const float vp = -(p2 + __shfl_xor(p2, 32));
    if (half == 0) { v_c0[n] = vc; v_pi[n] = vp; }
    float mc = vc, mp = vp;
    for (int off = 16; off; off >>= 1) {
        mc = fmaxf(mc, __shfl_xor(mc, off));
        mp = fmaxf(mp, __shfl_xor(mp, off));
    }
    if (lane == 0) { wmax_c0[wg * 4 + wid] = mc; wmax_pi[wg * 4 + wid] = mp; }
}

// ---- iters 1..5: evaluate cem_i against meanarr[i] (scale = 1.0).
__global__ void __launch_bounds__(256, 2) k_value(
        const float4* __restrict__ nz4, const float* __restrict__ target,
        const float* __restrict__ meanarr_i,
        float* __restrict__ v_out, float* __restrict__ wmax_out) {
    __shared__ float tgt[HAD], mnL[HAD];
    const int tid = threadIdx.x, wg = blockIdx.x;
    const int lane = tid & 63, wid = tid >> 6;
    const int half = lane >> 5;
    const int n = wg * 128 + wid * 32 + (lane & 31);

    float4 xs[9];
#pragma unroll
    for (int hh = 0; hh < 9; ++hh) xs[hh] = nz4[(size_t)(half * 9 + hh) * NS + n];

    if (tid < HAD) { tgt[tid] = target[tid]; mnL[tid] = meanarr_i[tid]; }
    __syncthreads();

    float a2 = 0.f;
#pragma unroll
    for (int hh = 0; hh < 9; ++hh) {
        const int h = half * 9 + hh;
        float c;
        c = clamp4f(mnL[h*4+0] + xs[hh].x) - tgt[h*4+0]; a2 += c*c;
        c = clamp4f(mnL[h*4+1] + xs[hh].y) - tgt[h*4+1]; a2 += c*c;
        c = clamp4f(mnL[h*4+2] + xs[hh].z) - tgt[h*4+2]; a2 += c*c;
        c = clamp4f(mnL[h*4+3] + xs[hh].w) - tgt[h*4+3]; a2 += c*c;
    }
    const float vc = -(a2 + __shfl_xor(a2, 32));
    if (half == 0) v_out[n] = vc;
    float m = vc;
    for (int off = 16; off; off >>= 1) m = fmaxf(m, __shfl_xor(m, off));
    if (lane == 0) wmax_out[wg * 4 + wid] = m;
}

// ---- 1-block hierarchical reduce of iteration `iter`:
//      gmax from chunk maxima -> survivors from passing chunks only ->
//      rank-select exact top-64 (2 barriers) -> softmax -> float4 gather ->
//      meanarr[iter+1].  is_last: exact argmax -> out.
__global__ void __launch_bounds__(1024) k_reduce(
        const float* __restrict__ pi, const float* __restrict__ noise_i,
        float* __restrict__ meanarr,
        const float* __restrict__ wmax_pi, const float* __restrict__ v_pi,
        const float* __restrict__ wmax_c, const float* __restrict__ v_c,
        float* __restrict__ out, int iter, int is_last) {
    __shared__ unsigned long long skey[SCAP];
    __shared__ unsigned long long top[64];
    __shared__ unsigned long long redk[16];
    __shared__ float buf[64 * 76];
    __shared__ float w64[64];
    __shared__ float mprev[HAD];
    __shared__ float redf[16];
    __shared__ unsigned s_fcnt;
    __shared__ float s_S, s_gmax;
    const int tid = threadIdx.x, lane = tid & 63, wid = tid >> 6;

    if (tid < HAD) mprev[tid] = meanarr[iter * HAD + tid];
    if (tid == 0) s_fcnt = 0u;
    __syncthreads();

    // ---- gmax (4 maxima loads per thread)
    {
        float g = fmaxf(fmaxf(wmax_pi[tid], wmax_pi[tid + 1024]),
                        fmaxf(wmax_c[tid], wmax_c[tid + 1024]));
        for (int off = 32; off; off >>= 1) g = fmaxf(g, __shfl_xor(g, off));
        if (lane == 0) redf[wid] = g;
        __syncthreads();
        if (tid == 0) {
            float x = redf[0];
            for (int q = 1; q < 16; ++q) x = fmaxf(x, redf[q]);
            s_gmax = x;
        }
        __syncthreads();
    }
    const float gmax = s_gmax, thr = gmax - DELTA;

    // ---- survivor collection from passing chunks only (2 chunks/thread/set)
#pragma unroll
    for (int r = 0; r < 2; ++r) {
        const int c = tid + r * 1024;
        if (wmax_pi[c] >= thr) {
            const float4* v4 = (const float4*)v_pi + c * 8;
            for (int q = 0; q < 8; ++q) {
                float4 x = v4[q];
                float vv[4] = {x.x, x.y, x.z, x.w};
#pragma unroll
                for (int c2 = 0; c2 < 4; ++c2)
                    if (vv[c2] >= thr) {
                        unsigned p = atomicAdd(&s_fcnt, 1u);
                        if (p < SCAP) skey[p] = packkey(vv[c2], (unsigned)(c * 32 + q * 4 + c2));
                    }
            }
        }
        if (wmax_c[c] >= thr) {
            const float4* v4 = (const float4*)v_c + c * 8;
            for (int q = 0; q < 8; ++q) {
                float4 x = v4[q];
                float vv[4] = {x.x, x.y, x.z, x.w};
#pragma unroll
                for (int c2 = 0; c2 < 4; ++c2)
                    if (vv[c2] >= thr) {
                        unsigned p = atomicAdd(&s_fcnt, 1u);
                        if (p < SCAP) skey[p] = packkey(vv[c2], (unsigned)(NS + c * 32 + q * 4 + c2));
                    }
            }
        }
    }
    __syncthreads();
    unsigned fc = s_fcnt; if (fc > SCAP) fc = SCAP;
    const float pscale = (iter == 0) ? 0.5f : 1.0f;

    if (is_last) {
        // ---- exact argmax over survivors (global max is among them)
        unsigned long long bk = 0ull;
        for (unsigned k = tid; k < fc; k += 1024) if (skey[k] > bk) bk = skey[k];
        for (int off = 32; off; off >>= 1) {
            unsigned long long ok = __shfl_xor(bk, off);
            if (ok > bk) bk = ok;
        }
        if (lane == 0) redk[wid] = bk;
        __syncthreads();
        if (tid == 0) {
            unsigned long long b = redk[0];
            for (int q = 1; q < 16; ++q) if (redk[q] > b) b = redk[q];
            redk[0] = b;
        }
        __syncthreads();
        const unsigned idx = (unsigned)~(unsigned)(redk[0] & 0xFFFFFFFFull);
        if (tid < HAD) {
            const int h = tid >> 2, aa = tid & 3;
            float o;
            if (idx < NS) o = pi[(size_t)h * NS * AD + (size_t)idx * AD + aa];
            else o = clamp4f(mprev[tid] + pscale * noise_i[(size_t)h * NS * AD + (size_t)(idx - NS) * AD + aa]);
            out[tid] = o;
        }
        return;
    }

    // ---- rank-selection: exact sorted top-64 in 2 barriers
    for (unsigned i = tid; i < fc; i += 1024) {
        unsigned long long k = skey[i];
        unsigned r = 0;
        for (unsigned j = 0; j < fc; ++j) r += (skey[j] > k) ? 1u : 0u;
        if (r < 64u) top[r] = k;
    }
    if (fc < 64u)
        for (unsigned r = fc + tid; r < 64u; r += 1024) top[r] = 0ull;
    __syncthreads();
    const int E = (fc < 64u) ? (int)fc : 64;

    // ---- softmax weights (wave 0, fixed order)
    if (tid < 64) {
        float we = (tid < E) ? expf(decf((unsigned)(top[tid] >> 32)) - gmax) : 0.0f;
        w64[tid] = we;
        float s = we;
        for (int off = 32; off; off >>= 1) s += __shfl_xor(s, off);
        if (tid == 0) s_S = s;
    }
    __syncthreads();
    const float invS = 1.0f / (s_S * (1.0f + 1e-9f));

    // ---- elite gather: 64 x 18 float4 over 1024 threads (~2 rounds)
    const float4* pi4 = (const float4*)pi;
    const float4* nz4 = (const float4*)noise_i;
    for (int el = tid; el < 64 * H; el += 1024) {
        const int e = el / H, h = el - e * H;
        float ax = 0.f, ay = 0.f, az = 0.f, aw = 0.f;
        if (e < E) {
            const unsigned idx = (unsigned)~(unsigned)(top[e] & 0xFFFFFFFFull);
            float4 a;
            if (idx < NS) {
                a = pi4[(size_t)h * NS + idx];
            } else {
                float4 nz = nz4[(size_t)h * NS + (idx - NS)];
                a.x = clamp4f(mprev[h*4+0] + pscale * nz.x);
                a.y = clamp4f(mprev[h*4+1] + pscale * nz.y);
                a.z = clamp4f(mprev[h*4+2] + pscale * nz.z);
                a.w = clamp4f(mprev[h*4+3] + pscale * nz.w);
            }
            const float we = w64[e];
            ax = we * a.x; ay = we * a.y; az = we * a.z; aw = we * a.w;
        }
        buf[e * 76 + h * 4 + 0] = ax;
        buf[e * 76 + h * 4 + 1] = ay;
        buf[e * 76 + h * 4 + 2] = az;
        buf[e * 76 + h * 4 + 3] = aw;
    }
    __syncthreads();
    if (tid < HAD) {
        float s = 0.f;
#pragma unroll 8
        for (int e = 0; e < 64; ++e) s += buf[e * 76 + tid];
        meanarr[(iter + 1) * HAD + tid] = 0.1f * mprev[tid] + 0.9f * (s * invS);
    }
}

extern "C" void kernel_launch(void* const* d_in, const int* in_sizes, int n_in,
                              void* d_out, int out_size, void* d_ws, size_t ws_size,
                              hipStream_t stream) {
    const float* pi     = (const float*)d_in[0];
    const float* noise  = (const float*)d_in[1];
    const float* target = (const float*)d_in[2];
    float* out = (float*)d_out;

    float* ws = (float*)d_ws;
    float* meanarr = ws;                                   // 8*72 (pad 1024)
    float* wmax_pi = ws + 1024;                            // NCH
    float* wmax_c  = wmax_pi + NCH;                        // 6*NCH
    float* v_pi    = wmax_c + 6 * NCH;                     // NS
    float* v_c     = v_pi + NS;                            // 6*NS

    k_value0<<<512, 256, 0, stream>>>((const float4*)pi, (const float4*)noise,
                                      target, meanarr, v_pi, wmax_pi, v_c, wmax_c);
    for (int i = 0; i < ITERS - 1; ++i) {
        const float* nzi = noise + (size_t)i * H * NS * AD;
        k_reduce<<<1, 1024, 0, stream>>>(pi, nzi, meanarr, wmax_pi, v_pi,
                                         wmax_c + (size_t)i * NCH,
                                         v_c + (size_t)i * NS, out, i, 0);
        const float* nzn = noise + (size_t)(i + 1) * H * NS * AD;
        k_value<<<512, 256, 0, stream>>>((const float4*)nzn, target,
                                         meanarr + (size_t)(i + 1) * HAD,
                                         v_c + (size_t)(i + 1) * NS,
                                         wmax_c + (size_t)(i + 1) * NCH);
    }
    k_reduce<<<1, 1024, 0, stream>>>(pi, noise + (size_t)5 * H * NS * AD, meanarr,
                                     wmax_pi, v_pi,
                                     wmax_c + (size_t)5 * NCH,
                                     v_c + (size_t)5 * NS, out, 5, 1);
}